// Round 10
// baseline (262.632 us; speedup 1.0000x reference)
//
#include <hip/hip_runtime.h>
#include <hip/hip_bf16.h>

#define B_ 8
#define S_ 4096
#define HID_ 640
#define KV_ 77
#define AU_ 16
#define CROSS_ 768
#define HEADS_ 10
#define DH_ 64
#define SCALE_ 0.125f

using f32x4 = __attribute__((ext_vector_type(4))) float;
using bf16x8 = __attribute__((ext_vector_type(8))) short;

__device__ __forceinline__ short bfc(float f) {
  __hip_bfloat16 h = __float2bfloat16(f);
  return __builtin_bit_cast(short, h);
}

__device__ __forceinline__ void gload16(const void* g, void* lds) {
  __builtin_amdgcn_global_load_lds(
      (const __attribute__((address_space(1))) void*)g,
      (__attribute__((address_space(3))) void*)lds, 16, 0, 0);
}

// ---------------------------------------------------------------- prior table
__global__ __launch_bounds__(256) void prior_k(float* prior) {
  int i = blockIdx.x * 256 + threadIdx.x;
  if (i < S_) {
    int yy = i >> 6, xx = i & 63;
    float lx = -1.f + 2.f * (float)xx / 63.f;
    float ly = -1.f + 2.f * (float)yy / 63.f;
    prior[i] = __expf(-(lx * lx + ly * ly) * (1.0f / 0.605f));
  }
}

// ---------------------------------------------------------------- f32 -> bf16
__global__ __launch_bounds__(256) void cvt_k(const float* in, short* out,
                                             int n8) {
  int i = blockIdx.x * 256 + threadIdx.x;
  if (i >= n8) return;
  const float4 a = *(const float4*)(in + (size_t)i * 8);
  const float4 b = *(const float4*)(in + (size_t)i * 8 + 4);
  bf16x8 v;
  v[0] = bfc(a.x); v[1] = bfc(a.y); v[2] = bfc(a.z); v[3] = bfc(a.w);
  v[4] = bfc(b.x); v[5] = bfc(b.y); v[6] = bfc(b.z); v[7] = bfc(b.w);
  *(bf16x8*)(out + (size_t)i * 8) = v;
}

// ------------------------------------------------- weight transpose + convert
__global__ __launch_bounds__(256) void wprep_k(
    const float* Wq, const float* Wk, const float* Wv, const float* Wauk,
    const float* Wauv, const float* Wout, short* Wqt, short* Wkt, short* Wvt,
    short* Waukt, short* Wauvt, short* Woutt) {
  const float* W;
  short* Wt;
  int K;
  switch (blockIdx.z) {
    case 0: W = Wq;   Wt = Wqt;   K = 640; break;
    case 1: W = Wk;   Wt = Wkt;   K = 768; break;
    case 2: W = Wv;   Wt = Wvt;   K = 768; break;
    case 3: W = Wauk; Wt = Waukt; K = 768; break;
    case 4: W = Wauv; Wt = Wauvt; K = 768; break;
    default: W = Wout; Wt = Woutt; K = 640; break;
  }
  int kt = blockIdx.y * 64, nt = blockIdx.x * 64;
  if (kt >= K) return;
  __shared__ short Tl[64][72];
  const int t = threadIdx.x;
#pragma unroll
  for (int j = 0; j < 16; ++j) {
    int i = t + j * 256;
    int r = i >> 6, c = i & 63;
    Tl[c][r] = bfc(W[(size_t)(kt + r) * 640 + nt + c]);
  }
  __syncthreads();
#pragma unroll
  for (int j = 0; j < 2; ++j) {
    int i = t + j * 256;
    int nl = i >> 3, c = i & 7;
    *(int4*)&Wt[(size_t)(nt + nl) * K + kt + c * 8] = *(int4*)&Tl[nl][c * 8];
  }
}

// ---------------------------------------------- big GEMM (R10: R6 + prefetch2)
// 256x128 tile, 512 threads (8 waves, 64x64/wave), BK=64, K=640 (10 K-tiles).
// 3-buffer LDS (144 KB), prefetch distance 2, ONE s_barrier per iter,
// counted vmcnt(6) before the barrier (each wave waits its own 6 loads for
// the oldest in-flight tile; barrier makes the tile collectively complete).
// Swizzle identical to R6 (verified 0 conflicts): row = 128 B = 8 slots of
// 16 B; physical slot s holds logical s^(r&7); read byteoff
// = (ks*64 + lg*16) ^ ((row&7)<<4).
template <bool EPI>
__device__ __forceinline__ void gemm256(const short* Abf, const short* Bt,
                                        void* Cout, const float* bias,
                                        const float* resid, int N, int m0,
                                        int n0) {
  __shared__ short Al[3][256 * 64];
  __shared__ short Bl[3][128 * 64];
  const int t = threadIdx.x;
  const int lane = t & 63;
  const int wave = t >> 6;  // 0..7
  const int l15 = lane & 15, lg = lane >> 4;
  const int wr = (wave >> 1) * 64;
  const int wc = (wave & 1) * 64;

  f32x4 z4 = {0.f, 0.f, 0.f, 0.f};
  f32x4 acc[4][4];
#pragma unroll
  for (int i = 0; i < 4; ++i)
#pragma unroll
    for (int j = 0; j < 4; ++j) acc[i][j] = z4;

  // stage tile (K-offset tile*64) into buffer buf: 6 gload16 per thread
  auto stage = [&](int tile, int buf) {
    const int k0 = tile * 64;
#pragma unroll
    for (int i = 0; i < 4; ++i) {
      int chunk = wave * 256 + i * 64 + lane;
      int r = chunk >> 3, s = chunk & 7;
      gload16(Abf + (size_t)(m0 + r) * 640 + k0 + ((s ^ (r & 7)) << 3),
              Al[buf] + (size_t)chunk * 8);
    }
#pragma unroll
    for (int i = 0; i < 2; ++i) {
      int chunk = wave * 128 + i * 64 + lane;
      int r = chunk >> 3, s = chunk & 7;
      gload16(Bt + (size_t)(n0 + r) * 640 + k0 + ((s ^ (r & 7)) << 3),
              Bl[buf] + (size_t)chunk * 8);
    }
  };

  // prologue: tiles 0,1 in flight (12 loads); wait oldest 6 -> tile 0 ready
  stage(0, 0);
  stage(1, 1);
  asm volatile("s_waitcnt vmcnt(6)" ::: "memory");
  __builtin_amdgcn_s_barrier();

  for (int it = 0; it < 10; ++it) {
    const int cur = it % 3;
    if (it < 8) stage(it + 2, (it + 2) % 3);

    const short* Ab = Al[cur];
    const short* Bb = Bl[cur];
#pragma unroll
    for (int ks = 0; ks < 2; ++ks) {
      bf16x8 af[4], bfr[4];
#pragma unroll
      for (int mi = 0; mi < 4; ++mi) {
        int row = wr + mi * 16 + l15;
        af[mi] = *(const bf16x8*)((const char*)(Ab + row * 64) +
                                  ((ks * 64 + lg * 16) ^ ((row & 7) << 4)));
      }
#pragma unroll
      for (int ni = 0; ni < 4; ++ni) {
        int row = wc + ni * 16 + l15;
        bfr[ni] = *(const bf16x8*)((const char*)(Bb + row * 64) +
                                   ((ks * 64 + lg * 16) ^ ((row & 7) << 4)));
      }
      __builtin_amdgcn_s_setprio(1);
#pragma unroll
      for (int mi = 0; mi < 4; ++mi)
#pragma unroll
        for (int ni = 0; ni < 4; ++ni)
          acc[mi][ni] = __builtin_amdgcn_mfma_f32_16x16x32_bf16(
              af[mi], bfr[ni], acc[mi][ni], 0, 0, 0);
      __builtin_amdgcn_s_setprio(0);
    }

    if (it < 8) {
      asm volatile("s_waitcnt vmcnt(6)" ::: "memory");  // tile it+1 landed
    } else if (it == 8) {
      asm volatile("s_waitcnt vmcnt(0)" ::: "memory");  // tile 9 landed
    }
    if (it < 9) __builtin_amdgcn_s_barrier();
  }

  // epilogue
#pragma unroll
  for (int mi = 0; mi < 4; ++mi) {
#pragma unroll
    for (int j = 0; j < 4; ++j) {
      int row = m0 + wr + mi * 16 + lg * 4 + j;
#pragma unroll
      for (int ni = 0; ni < 4; ++ni) {
        int col = n0 + wc + ni * 16 + l15;
        size_t idx = (size_t)row * N + col;
        float val = acc[mi][ni][j];
        if (EPI) {
          ((float*)Cout)[idx] = val + bias[col] + resid[idx];
        } else {
          ((short*)Cout)[idx] = bfc(val);
        }
      }
    }
  }
}

__global__ __launch_bounds__(512, 2) void gemm_q_k(const short* A,
                                                   const short* Bt, short* C) {
  gemm256<false>(A, Bt, C, nullptr, nullptr, HID_, blockIdx.x * 256,
                 blockIdx.y * 128);
}

__global__ __launch_bounds__(512, 2) void gemm_out_k(const short* A,
                                                     const short* Bt, float* C,
                                                     const float* bias,
                                                     const float* resid) {
  gemm256<true>(A, Bt, C, bias, resid, HID_, blockIdx.x * 256,
                blockIdx.y * 128);
}

// ---------------------------------------------------------------- small GEMM
__device__ __forceinline__ void gemm_small(const float* A32, const short* Bt,
                                           short* Cout, int M, int K, int N,
                                           int m0, int n0) {
  __shared__ short Al[128][72];
  __shared__ short Bl[128][72];
  const int t = threadIdx.x;
  const int lane = t & 63;
  const int wave = t >> 6;
  const int l15 = lane & 15, lg = lane >> 4;
  const int wr = (wave >> 1) * 64, wc = (wave & 1) * 64;

  f32x4 z4 = {0.f, 0.f, 0.f, 0.f};
  f32x4 acc[4][4];
#pragma unroll
  for (int i = 0; i < 4; ++i)
#pragma unroll
    for (int j = 0; j < 4; ++j) acc[i][j] = z4;

  for (int k0 = 0; k0 < K; k0 += 64) {
#pragma unroll
    for (int j = 0; j < 8; ++j) {
      int i = t + j * 256;
      int r = i >> 4, q = i & 15;
      int row = m0 + r;
      float4 v = {0.f, 0.f, 0.f, 0.f};
      if (row < M) v = *(const float4*)(A32 + (size_t)row * K + k0 + q * 4);
      short4 s;
      s.x = bfc(v.x);
      s.y = bfc(v.y);
      s.z = bfc(v.z);
      s.w = bfc(v.w);
      *(short4*)&Al[r][q * 4] = s;
    }
#pragma unroll
    for (int j = 0; j < 4; ++j) {
      int i = t + j * 256;
      int row = i >> 3, c = i & 7;
      *(int4*)&Bl[row][c * 8] =
          *(const int4*)(Bt + (size_t)(n0 + row) * K + k0 + c * 8);
    }
    __syncthreads();
#pragma unroll
    for (int ks = 0; ks < 64; ks += 32) {
      bf16x8 af[4], bfr[4];
#pragma unroll
      for (int mi = 0; mi < 4; ++mi)
        af[mi] = *(const bf16x8*)&Al[wr + mi * 16 + l15][ks + lg * 8];
#pragma unroll
      for (int ni = 0; ni < 4; ++ni)
        bfr[ni] = *(const bf16x8*)&Bl[wc + ni * 16 + l15][ks + lg * 8];
#pragma unroll
      for (int mi = 0; mi < 4; ++mi)
#pragma unroll
        for (int ni = 0; ni < 4; ++ni)
          acc[mi][ni] = __builtin_amdgcn_mfma_f32_16x16x32_bf16(
              af[mi], bfr[ni], acc[mi][ni], 0, 0, 0);
    }
    __syncthreads();
  }
#pragma unroll
  for (int mi = 0; mi < 4; ++mi) {
#pragma unroll
    for (int j = 0; j < 4; ++j) {
      int row = m0 + wr + mi * 16 + lg * 4 + j;
      if (row >= M) continue;
#pragma unroll
      for (int ni = 0; ni < 4; ++ni) {
        int col = n0 + wc + ni * 16 + l15;
        Cout[(size_t)row * N + col] = bfc(acc[mi][ni][j]);
      }
    }
  }
}

__global__ __launch_bounds__(256) void proj4_k(const float* enc,
                                               const float* au,
                                               const short* Wkt,
                                               const short* Wvt,
                                               const short* Waukt,
                                               const short* Wauvt, short* Kb,
                                               short* Vb, short* AKb,
                                               short* AVb) {
  int z = blockIdx.z;
  const float* A = (z < 2) ? enc : au;
  const short* Bt = (z == 0) ? Wkt : (z == 1) ? Wvt : (z == 2) ? Waukt : Wauvt;
  short* O = (z == 0) ? Kb : (z == 1) ? Vb : (z == 2) ? AKb : AVb;
  int M = (z < 2) ? (B_ * KV_) : (B_ * AU_);
  if ((int)blockIdx.x * 128 >= M) return;
  gemm_small(A, Bt, O, M, CROSS_, HID_, blockIdx.x * 128, blockIdx.y * 128);
}

// ---------------------------------------------------------------- attention
// one block per (512-row q-chunk, h, b); K/V/AU staged ONCE, 8-iter Q loop.
// Ob may alias Qb (in-place, race-free as analyzed in R6).
__global__ __launch_bounds__(256) void attn_k(const short* Qb, const short* Kb,
                                              const short* Vb, const short* AKb,
                                              const short* AVb,
                                              const float* prior, short* Ob,
                                              const float* temp,
                                              const float* gate) {
  __shared__ short Qt[64 * 64];   // linear, XOR-swizzled (gload16 dest)
  __shared__ short Kl[80][72];
  __shared__ short Vt[64][104];
  __shared__ short Pl[64][104];
  __shared__ short AUKl[16][72];
  __shared__ short AUVt[64][40];
  __shared__ short Ml[64][40];

  const int t = threadIdx.x;
  const int lane = t & 63, wave = t >> 6;
  const int l15 = lane & 15, lg = lane >> 4;
  const int qbase = blockIdx.x * 512;
  const int h = blockIdx.y;
  const int b = blockIdx.z;
  const int rw = wave * 16;
  f32x4 z4 = {0.f, 0.f, 0.f, 0.f};

  for (int i = t; i < 64 * 27; i += 256) {
    int r = i / 27, c = i - r * 27;
    Vt[r][77 + c] = 0;
  }
  for (int i = t; i < 64 * 8; i += 256) {
    int r = i >> 3, c = i & 7;
    *(int*)&Pl[r][80 + c * 2] = 0;
  }
  for (int i = t; i < 64 * 12; i += 256) {
    int r = i / 12, c = i - r * 12;
    *(int*)&AUVt[r][16 + c * 2] = 0;
  }
  for (int i = t; i < 64 * 12; i += 256) {
    int r = i / 12, c = i - r * 12;
    *(int*)&Ml[r][16 + c * 2] = 0;
  }
#pragma unroll
  for (int j = 0; j < 3; ++j) {
    int i = t + j * 256;
    if (i < KV_ * 8) {
      int r = i >> 3, c8 = i & 7;
      *(int4*)&Kl[r][c8 * 8] =
          *(const int4*)(Kb + (size_t)(b * KV_ + r) * HID_ + h * DH_ + c8 * 8);
    }
  }
  for (int i = t; i < KV_ * DH_; i += 256) {
    int d = i & 63, kv = i >> 6;
    Vt[d][kv] = Vb[(size_t)(b * KV_ + kv) * HID_ + h * DH_ + d];
  }
  if (t < AU_ * 8) {
    int r = t >> 3, c8 = t & 7;
    *(int4*)&AUKl[r][c8 * 8] =
        *(const int4*)(AKb + (size_t)(b * AU_ + r) * HID_ + h * DH_ + c8 * 8);
  }
  for (int i = t; i < AU_ * DH_; i += 256) {
    int d = i & 63, a = i >> 6;
    AUVt[d][a] = AVb[(size_t)(b * AU_ + a) * HID_ + h * DH_ + d];
  }

  const float invT = 1.f / (fabsf(temp[0]) + 1e-6f);
  const float g = gate[0];  // AU_SCALE = 1

  for (int qi = 0; qi < 8; ++qi) {
    const int q0 = qbase + qi * 64;
#pragma unroll
    for (int i2 = 0; i2 < 2; ++i2) {
      int chunk = wave * 128 + i2 * 64 + lane;
      int r = chunk >> 3, s = chunk & 7;
      const short* src = Qb + (size_t)(b * S_ + q0 + r) * HID_ + h * DH_ +
                         ((s ^ (r & 7)) << 3);
      gload16(src, Qt + (wave * 128 + i2 * 64) * 8);
    }
    __syncthreads();

    f32x4 accS[5], accA = z4;
#pragma unroll
    for (int c = 0; c < 5; ++c) accS[c] = z4;
#pragma unroll
    for (int ks = 0; ks < 2; ++ks) {
      const char* qrow = (const char*)(Qt + (rw + l15) * 64);
      bf16x8 aq =
          *(const bf16x8*)(qrow + ((ks * 64 + lg * 16) ^ ((l15 & 7) << 4)));
#pragma unroll
      for (int c = 0; c < 5; ++c) {
        bf16x8 bk = *(const bf16x8*)&Kl[c * 16 + l15][ks * 32 + lg * 8];
        accS[c] =
            __builtin_amdgcn_mfma_f32_16x16x32_bf16(aq, bk, accS[c], 0, 0, 0);
      }
      bf16x8 ba = *(const bf16x8*)&AUKl[l15][ks * 32 + lg * 8];
      accA = __builtin_amdgcn_mfma_f32_16x16x32_bf16(aq, ba, accA, 0, 0, 0);
    }

#pragma unroll
    for (int j = 0; j < 4; ++j) {
      float v[5];
      float m = -1e30f;
#pragma unroll
      for (int c = 0; c < 5; ++c) {
        int col = c * 16 + l15;
        v[c] = (col < KV_) ? accS[c][j] * SCALE_ : -1e30f;
        m = fmaxf(m, v[c]);
      }
#pragma unroll
      for (int off = 1; off < 16; off <<= 1) m = fmaxf(m, __shfl_xor(m, off));
      float p[5];
      float s = 0.f;
#pragma unroll
      for (int c = 0; c < 5; ++c) {
        p[c] = (v[c] > -1e29f) ? __expf(v[c] - m) : 0.f;
        s += p[c];
      }
#pragma unroll
      for (int off = 1; off < 16; off <<= 1) s += __shfl_xor(s, off);
      float inv = 1.f / s;
      int r = rw + lg * 4 + j;
#pragma unroll
      for (int c = 0; c < 5; ++c) Pl[r][c * 16 + l15] = bfc(p[c] * inv);
      float as = accA[j] * SCALE_ * invT;
      float sg = 1.f / (1.f + __expf(-as));
      float mv = sg * prior[q0 + r] * 0.9f + 0.1f;
      Ml[r][l15] = bfc(mv);
    }

    f32x4 accO[4], accAO[4];
#pragma unroll
    for (int c = 0; c < 4; ++c) {
      accO[c] = z4;
      accAO[c] = z4;
    }
#pragma unroll
    for (int kk = 0; kk < 96; kk += 32) {
      bf16x8 ap = *(const bf16x8*)&Pl[rw + l15][kk + lg * 8];
#pragma unroll
      for (int c = 0; c < 4; ++c) {
        bf16x8 bv = *(const bf16x8*)&Vt[c * 16 + l15][kk + lg * 8];
        accO[c] =
            __builtin_amdgcn_mfma_f32_16x16x32_bf16(ap, bv, accO[c], 0, 0, 0);
      }
    }
    {
      bf16x8 am = *(const bf16x8*)&Ml[rw + l15][lg * 8];
#pragma unroll
      for (int c = 0; c < 4; ++c) {
        bf16x8 bv = *(const bf16x8*)&AUVt[c * 16 + l15][lg * 8];
        accAO[c] =
            __builtin_amdgcn_mfma_f32_16x16x32_bf16(am, bv, accAO[c], 0, 0, 0);
      }
    }
#pragma unroll
    for (int c = 0; c < 4; ++c)
#pragma unroll
      for (int j = 0; j < 4; ++j) {
        int r = rw + lg * 4 + j;
        Pl[r][c * 16 + l15] = bfc(accO[c][j] + g * accAO[c][j]);
      }
    __syncthreads();
#pragma unroll
    for (int i2 = 0; i2 < 2; ++i2) {
      int idx = t + i2 * 256;
      int r = idx >> 3, cg = idx & 7;
      *(int4*)(Ob + (size_t)(b * S_ + q0 + r) * HID_ + h * DH_ + cg * 8) =
          *(const int4*)&Pl[r][cg * 8];
    }
  }
}

// ---------------------------------------------------------------- launcher
extern "C" void kernel_launch(void* const* d_in, const int* in_sizes, int n_in,
                              void* d_out, int out_size, void* d_ws,
                              size_t ws_size, hipStream_t stream) {
  const float* hs = (const float*)d_in[0];
  const float* enc = (const float*)d_in[1];
  const float* au = (const float*)d_in[2];
  const float* Wq = (const float*)d_in[3];
  const float* Wk = (const float*)d_in[4];
  const float* Wv = (const float*)d_in[5];
  const float* Wauk = (const float*)d_in[6];
  const float* Wauv = (const float*)d_in[7];
  const float* Wout = (const float*)d_in[8];
  const float* bout = (const float*)d_in[9];
  const float* temp = (const float*)d_in[10];
  const float* gate = (const float*)d_in[11];
  float* out = (float*)d_out;
  char* ws = (char*)d_ws;

  const size_t szK = (size_t)B_ * KV_ * HID_ * 2;   // 788480
  const size_t szAU = (size_t)B_ * AU_ * HID_ * 2;  // 163840
  const size_t szW640 = (size_t)HID_ * HID_ * 2;    // 819200
  const size_t szW768 = (size_t)HID_ * CROSS_ * 2;  // 983040

  size_t off = 0;
  float* prior = (float*)(ws + off);  off += 16384;
  short* Kbf = (short*)(ws + off);    off += szK;
  short* Vbf = (short*)(ws + off);    off += szK;
  short* AUKbf = (short*)(ws + off);  off += szAU;
  short* AUVbf = (short*)(ws + off);  off += szAU;
  short* Wqt = (short*)(ws + off);    off += szW640;
  short* Wkt = (short*)(ws + off);    off += szW768;
  short* Wvt = (short*)(ws + off);    off += szW768;
  short* Waukt = (short*)(ws + off);  off += szW768;
  short* Wauvt = (short*)(ws + off);  off += szW768;
  short* Woutt = (short*)(ws + off);  off += szW640;
  short* Qbf = (short*)(ws + off);    // 41.94 MB; total ws ~49.5 MB
  short* Abf = Qbf;                   // ALIAS: attn overwrites Q in place
  short* hsb = (short*)d_out;         // d_out head as scratch (dead before
                                      // gemm_out_k writes real output)

  prior_k<<<16, 256, 0, stream>>>(prior);
  wprep_k<<<dim3(10, 12, 6), 256, 0, stream>>>(Wq, Wk, Wv, Wauk, Wauv, Wout,
                                               Wqt, Wkt, Wvt, Waukt, Wauvt,
                                               Woutt);
  cvt_k<<<10240, 256, 0, stream>>>(hs, hsb, (B_ * S_ * HID_) / 8);
  proj4_k<<<dim3(5, 5, 4), 256, 0, stream>>>(enc, au, Wkt, Wvt, Waukt, Wauvt,
                                             Kbf, Vbf, AUKbf, AUVbf);
  gemm_q_k<<<dim3(128, 5), 512, 0, stream>>>(hsb, Wqt, Qbf);
  attn_k<<<dim3(8, HEADS_, B_), 256, 0, stream>>>(Qbf, Kbf, Vbf, AUKbf, AUVbf,
                                                  prior, Abf, temp, gate);
  gemm_out_k<<<dim3(128, 5), 512, 0, stream>>>(Abf, Woutt, out, bout, hs);
}

// Round 11
// 248.787 us; speedup vs baseline: 1.0556x; 1.0556x over previous
//
#include <hip/hip_runtime.h>
#include <hip/hip_bf16.h>

#define B_ 8
#define S_ 4096
#define HID_ 640
#define KV_ 77
#define AU_ 16
#define CROSS_ 768
#define HEADS_ 10
#define DH_ 64
#define SCALE_ 0.125f

using f32x4 = __attribute__((ext_vector_type(4))) float;
using bf16x8 = __attribute__((ext_vector_type(8))) short;

__device__ __forceinline__ short bfc(float f) {
  __hip_bfloat16 h = __float2bfloat16(f);
  return __builtin_bit_cast(short, h);
}

__device__ __forceinline__ void gload16(const void* g, void* lds) {
  __builtin_amdgcn_global_load_lds(
      (const __attribute__((address_space(1))) void*)g,
      (__attribute__((address_space(3))) void*)lds, 16, 0, 0);
}

// ---------------------------------------------------------------- prior table
__global__ __launch_bounds__(256) void prior_k(float* prior) {
  int i = blockIdx.x * 256 + threadIdx.x;
  if (i < S_) {
    int yy = i >> 6, xx = i & 63;
    float lx = -1.f + 2.f * (float)xx / 63.f;
    float ly = -1.f + 2.f * (float)yy / 63.f;
    prior[i] = __expf(-(lx * lx + ly * ly) * (1.0f / 0.605f));
  }
}

// ---------------------------------------------------------------- f32 -> bf16
__global__ __launch_bounds__(256) void cvt_k(const float* in, short* out,
                                             int n8) {
  int i = blockIdx.x * 256 + threadIdx.x;
  if (i >= n8) return;
  const float4 a = *(const float4*)(in + (size_t)i * 8);
  const float4 b = *(const float4*)(in + (size_t)i * 8 + 4);
  bf16x8 v;
  v[0] = bfc(a.x); v[1] = bfc(a.y); v[2] = bfc(a.z); v[3] = bfc(a.w);
  v[4] = bfc(b.x); v[5] = bfc(b.y); v[6] = bfc(b.z); v[7] = bfc(b.w);
  *(bf16x8*)(out + (size_t)i * 8) = v;
}

// ------------------------------------------------- weight transpose + convert
__global__ __launch_bounds__(256) void wprep_k(
    const float* Wq, const float* Wk, const float* Wv, const float* Wauk,
    const float* Wauv, const float* Wout, short* Wqt, short* Wkt, short* Wvt,
    short* Waukt, short* Wauvt, short* Woutt) {
  const float* W;
  short* Wt;
  int K;
  switch (blockIdx.z) {
    case 0: W = Wq;   Wt = Wqt;   K = 640; break;
    case 1: W = Wk;   Wt = Wkt;   K = 768; break;
    case 2: W = Wv;   Wt = Wvt;   K = 768; break;
    case 3: W = Wauk; Wt = Waukt; K = 768; break;
    case 4: W = Wauv; Wt = Wauvt; K = 768; break;
    default: W = Wout; Wt = Woutt; K = 640; break;
  }
  int kt = blockIdx.y * 64, nt = blockIdx.x * 64;
  if (kt >= K) return;
  __shared__ short Tl[64][72];
  const int t = threadIdx.x;
#pragma unroll
  for (int j = 0; j < 16; ++j) {
    int i = t + j * 256;
    int r = i >> 6, c = i & 63;
    Tl[c][r] = bfc(W[(size_t)(kt + r) * 640 + nt + c]);
  }
  __syncthreads();
#pragma unroll
  for (int j = 0; j < 2; ++j) {
    int i = t + j * 256;
    int nl = i >> 3, c = i & 7;
    *(int4*)&Wt[(size_t)(nt + nl) * K + kt + c * 8] = *(int4*)&Tl[nl][c * 8];
  }
}

// ---------------------------------------------- big GEMM (R11: R6 + N160)
// 256x160 tile, 512 threads (8 waves: 4M x 2N, 64x80/wave), BK=64, K=640.
// Single-buffer LDS (52 KB), gload16 staging, plain __syncthreads loop —
// EXACTLY the R6-proven inner structure; only the N-tile width changed so
// grid = 128x4 = 512 blocks (no scheduling tail).
// Swizzle (verified 0 conflicts at BK=64): row = 128 B = 8 slots of 16 B;
// physical slot s holds logical s^(r&7); read byteoff
// = (ks*64 + lg*16) ^ ((row&7)<<4).
template <bool EPI>
__device__ __forceinline__ void gemm256(const short* Abf, const short* Bt,
                                        void* Cout, const float* bias,
                                        const float* resid, int N, int m0,
                                        int n0) {
  __shared__ short Al[256 * 64];
  __shared__ short Bl[160 * 64];
  const int t = threadIdx.x;
  const int lane = t & 63;
  const int wave = t >> 6;  // 0..7
  const int l15 = lane & 15, lg = lane >> 4;
  const int wr = (wave >> 1) * 64;  // 0,64,128,192
  const int wc = (wave & 1) * 80;   // 0,80

  f32x4 z4 = {0.f, 0.f, 0.f, 0.f};
  f32x4 acc[4][5];
#pragma unroll
  for (int i = 0; i < 4; ++i)
#pragma unroll
    for (int j = 0; j < 5; ++j) acc[i][j] = z4;

  for (int k0 = 0; k0 < 640; k0 += 64) {
    // ---- stage A [256][64]: 2048 chunks of 16 B, 4/thread
#pragma unroll
    for (int i = 0; i < 4; ++i) {
      int chunk = t + i * 512;
      int r = chunk >> 3, s = chunk & 7;
      gload16(Abf + (size_t)(m0 + r) * 640 + k0 + ((s ^ (r & 7)) << 3),
              Al + (size_t)chunk * 8);
    }
    // ---- stage B [160][64]: 1280 chunks, 2-3/thread
#pragma unroll
    for (int i = 0; i < 3; ++i) {
      int chunk = t + i * 512;
      if (chunk < 1280) {
        int r = chunk >> 3, s = chunk & 7;
        gload16(Bt + (size_t)(n0 + r) * 640 + k0 + ((s ^ (r & 7)) << 3),
                Bl + (size_t)chunk * 8);
      }
    }
    __syncthreads();
#pragma unroll
    for (int ks = 0; ks < 2; ++ks) {
      bf16x8 af[4], bfr[5];
#pragma unroll
      for (int mi = 0; mi < 4; ++mi) {
        int row = wr + mi * 16 + l15;
        af[mi] = *(const bf16x8*)((const char*)(Al + row * 64) +
                                  ((ks * 64 + lg * 16) ^ ((row & 7) << 4)));
      }
#pragma unroll
      for (int ni = 0; ni < 5; ++ni) {
        int row = wc + ni * 16 + l15;
        bfr[ni] = *(const bf16x8*)((const char*)(Bl + row * 64) +
                                   ((ks * 64 + lg * 16) ^ ((row & 7) << 4)));
      }
#pragma unroll
      for (int mi = 0; mi < 4; ++mi)
#pragma unroll
        for (int ni = 0; ni < 5; ++ni)
          acc[mi][ni] = __builtin_amdgcn_mfma_f32_16x16x32_bf16(
              af[mi], bfr[ni], acc[mi][ni], 0, 0, 0);
    }
    __syncthreads();
  }
  // epilogue
#pragma unroll
  for (int mi = 0; mi < 4; ++mi) {
#pragma unroll
    for (int j = 0; j < 4; ++j) {
      int row = m0 + wr + mi * 16 + lg * 4 + j;
#pragma unroll
      for (int ni = 0; ni < 5; ++ni) {
        int col = n0 + wc + ni * 16 + l15;
        size_t idx = (size_t)row * N + col;
        float val = acc[mi][ni][j];
        if (EPI) {
          ((float*)Cout)[idx] = val + bias[col] + resid[idx];
        } else {
          ((short*)Cout)[idx] = bfc(val);
        }
      }
    }
  }
}

__global__ __launch_bounds__(512, 2) void gemm_q_k(const short* A,
                                                   const short* Bt, short* C) {
  gemm256<false>(A, Bt, C, nullptr, nullptr, HID_, blockIdx.x * 256,
                 blockIdx.y * 160);
}

__global__ __launch_bounds__(512, 2) void gemm_out_k(const short* A,
                                                     const short* Bt, float* C,
                                                     const float* bias,
                                                     const float* resid) {
  gemm256<true>(A, Bt, C, bias, resid, HID_, blockIdx.x * 256,
                blockIdx.y * 160);
}

// ---------------------------------------------------------------- small GEMM
__device__ __forceinline__ void gemm_small(const float* A32, const short* Bt,
                                           short* Cout, int M, int K, int N,
                                           int m0, int n0) {
  __shared__ short Al[128][72];
  __shared__ short Bl[128][72];
  const int t = threadIdx.x;
  const int lane = t & 63;
  const int wave = t >> 6;
  const int l15 = lane & 15, lg = lane >> 4;
  const int wr = (wave >> 1) * 64, wc = (wave & 1) * 64;

  f32x4 z4 = {0.f, 0.f, 0.f, 0.f};
  f32x4 acc[4][4];
#pragma unroll
  for (int i = 0; i < 4; ++i)
#pragma unroll
    for (int j = 0; j < 4; ++j) acc[i][j] = z4;

  for (int k0 = 0; k0 < K; k0 += 64) {
#pragma unroll
    for (int j = 0; j < 8; ++j) {
      int i = t + j * 256;
      int r = i >> 4, q = i & 15;
      int row = m0 + r;
      float4 v = {0.f, 0.f, 0.f, 0.f};
      if (row < M) v = *(const float4*)(A32 + (size_t)row * K + k0 + q * 4);
      short4 s;
      s.x = bfc(v.x);
      s.y = bfc(v.y);
      s.z = bfc(v.z);
      s.w = bfc(v.w);
      *(short4*)&Al[r][q * 4] = s;
    }
#pragma unroll
    for (int j = 0; j < 4; ++j) {
      int i = t + j * 256;
      int row = i >> 3, c = i & 7;
      *(int4*)&Bl[row][c * 8] =
          *(const int4*)(Bt + (size_t)(n0 + row) * K + k0 + c * 8);
    }
    __syncthreads();
#pragma unroll
    for (int ks = 0; ks < 64; ks += 32) {
      bf16x8 af[4], bfr[4];
#pragma unroll
      for (int mi = 0; mi < 4; ++mi)
        af[mi] = *(const bf16x8*)&Al[wr + mi * 16 + l15][ks + lg * 8];
#pragma unroll
      for (int ni = 0; ni < 4; ++ni)
        bfr[ni] = *(const bf16x8*)&Bl[wc + ni * 16 + l15][ks + lg * 8];
#pragma unroll
      for (int mi = 0; mi < 4; ++mi)
#pragma unroll
        for (int ni = 0; ni < 4; ++ni)
          acc[mi][ni] = __builtin_amdgcn_mfma_f32_16x16x32_bf16(
              af[mi], bfr[ni], acc[mi][ni], 0, 0, 0);
    }
    __syncthreads();
  }
#pragma unroll
  for (int mi = 0; mi < 4; ++mi) {
#pragma unroll
    for (int j = 0; j < 4; ++j) {
      int row = m0 + wr + mi * 16 + lg * 4 + j;
      if (row >= M) continue;
#pragma unroll
      for (int ni = 0; ni < 4; ++ni) {
        int col = n0 + wc + ni * 16 + l15;
        Cout[(size_t)row * N + col] = bfc(acc[mi][ni][j]);
      }
    }
  }
}

__global__ __launch_bounds__(256) void proj4_k(const float* enc,
                                               const float* au,
                                               const short* Wkt,
                                               const short* Wvt,
                                               const short* Waukt,
                                               const short* Wauvt, short* Kb,
                                               short* Vb, short* AKb,
                                               short* AVb) {
  int z = blockIdx.z;
  const float* A = (z < 2) ? enc : au;
  const short* Bt = (z == 0) ? Wkt : (z == 1) ? Wvt : (z == 2) ? Waukt : Wauvt;
  short* O = (z == 0) ? Kb : (z == 1) ? Vb : (z == 2) ? AKb : AVb;
  int M = (z < 2) ? (B_ * KV_) : (B_ * AU_);
  if ((int)blockIdx.x * 128 >= M) return;
  gemm_small(A, Bt, O, M, CROSS_, HID_, blockIdx.x * 128, blockIdx.y * 128);
}

// ---------------------------------------------------------------- attention
// one block per (512-row q-chunk, h, b); K/V/AU staged ONCE, 8-iter Q loop.
// Ob may alias Qb (in-place, race-free as analyzed in R6).
__global__ __launch_bounds__(256) void attn_k(const short* Qb, const short* Kb,
                                              const short* Vb, const short* AKb,
                                              const short* AVb,
                                              const float* prior, short* Ob,
                                              const float* temp,
                                              const float* gate) {
  __shared__ short Qt[64 * 64];   // linear, XOR-swizzled (gload16 dest)
  __shared__ short Kl[80][72];
  __shared__ short Vt[64][104];
  __shared__ short Pl[64][104];
  __shared__ short AUKl[16][72];
  __shared__ short AUVt[64][40];
  __shared__ short Ml[64][40];

  const int t = threadIdx.x;
  const int lane = t & 63, wave = t >> 6;
  const int l15 = lane & 15, lg = lane >> 4;
  const int qbase = blockIdx.x * 512;
  const int h = blockIdx.y;
  const int b = blockIdx.z;
  const int rw = wave * 16;
  f32x4 z4 = {0.f, 0.f, 0.f, 0.f};

  for (int i = t; i < 64 * 27; i += 256) {
    int r = i / 27, c = i - r * 27;
    Vt[r][77 + c] = 0;
  }
  for (int i = t; i < 64 * 8; i += 256) {
    int r = i >> 3, c = i & 7;
    *(int*)&Pl[r][80 + c * 2] = 0;
  }
  for (int i = t; i < 64 * 12; i += 256) {
    int r = i / 12, c = i - r * 12;
    *(int*)&AUVt[r][16 + c * 2] = 0;
  }
  for (int i = t; i < 64 * 12; i += 256) {
    int r = i / 12, c = i - r * 12;
    *(int*)&Ml[r][16 + c * 2] = 0;
  }
#pragma unroll
  for (int j = 0; j < 3; ++j) {
    int i = t + j * 256;
    if (i < KV_ * 8) {
      int r = i >> 3, c8 = i & 7;
      *(int4*)&Kl[r][c8 * 8] =
          *(const int4*)(Kb + (size_t)(b * KV_ + r) * HID_ + h * DH_ + c8 * 8);
    }
  }
  for (int i = t; i < KV_ * DH_; i += 256) {
    int d = i & 63, kv = i >> 6;
    Vt[d][kv] = Vb[(size_t)(b * KV_ + kv) * HID_ + h * DH_ + d];
  }
  if (t < AU_ * 8) {
    int r = t >> 3, c8 = t & 7;
    *(int4*)&AUKl[r][c8 * 8] =
        *(const int4*)(AKb + (size_t)(b * AU_ + r) * HID_ + h * DH_ + c8 * 8);
  }
  for (int i = t; i < AU_ * DH_; i += 256) {
    int d = i & 63, a = i >> 6;
    AUVt[d][a] = AVb[(size_t)(b * AU_ + a) * HID_ + h * DH_ + d];
  }

  const float invT = 1.f / (fabsf(temp[0]) + 1e-6f);
  const float g = gate[0];  // AU_SCALE = 1

  for (int qi = 0; qi < 8; ++qi) {
    const int q0 = qbase + qi * 64;
#pragma unroll
    for (int i2 = 0; i2 < 2; ++i2) {
      int chunk = wave * 128 + i2 * 64 + lane;
      int r = chunk >> 3, s = chunk & 7;
      const short* src = Qb + (size_t)(b * S_ + q0 + r) * HID_ + h * DH_ +
                         ((s ^ (r & 7)) << 3);
      gload16(src, Qt + (wave * 128 + i2 * 64) * 8);
    }
    __syncthreads();

    f32x4 accS[5], accA = z4;
#pragma unroll
    for (int c = 0; c < 5; ++c) accS[c] = z4;
#pragma unroll
    for (int ks = 0; ks < 2; ++ks) {
      const char* qrow = (const char*)(Qt + (rw + l15) * 64);
      bf16x8 aq =
          *(const bf16x8*)(qrow + ((ks * 64 + lg * 16) ^ ((l15 & 7) << 4)));
#pragma unroll
      for (int c = 0; c < 5; ++c) {
        bf16x8 bk = *(const bf16x8*)&Kl[c * 16 + l15][ks * 32 + lg * 8];
        accS[c] =
            __builtin_amdgcn_mfma_f32_16x16x32_bf16(aq, bk, accS[c], 0, 0, 0);
      }
      bf16x8 ba = *(const bf16x8*)&AUKl[l15][ks * 32 + lg * 8];
      accA = __builtin_amdgcn_mfma_f32_16x16x32_bf16(aq, ba, accA, 0, 0, 0);
    }

#pragma unroll
    for (int j = 0; j < 4; ++j) {
      float v[5];
      float m = -1e30f;
#pragma unroll
      for (int c = 0; c < 5; ++c) {
        int col = c * 16 + l15;
        v[c] = (col < KV_) ? accS[c][j] * SCALE_ : -1e30f;
        m = fmaxf(m, v[c]);
      }
#pragma unroll
      for (int off = 1; off < 16; off <<= 1) m = fmaxf(m, __shfl_xor(m, off));
      float p[5];
      float s = 0.f;
#pragma unroll
      for (int c = 0; c < 5; ++c) {
        p[c] = (v[c] > -1e29f) ? __expf(v[c] - m) : 0.f;
        s += p[c];
      }
#pragma unroll
      for (int off = 1; off < 16; off <<= 1) s += __shfl_xor(s, off);
      float inv = 1.f / s;
      int r = rw + lg * 4 + j;
#pragma unroll
      for (int c = 0; c < 5; ++c) Pl[r][c * 16 + l15] = bfc(p[c] * inv);
      float as = accA[j] * SCALE_ * invT;
      float sg = 1.f / (1.f + __expf(-as));
      float mv = sg * prior[q0 + r] * 0.9f + 0.1f;
      Ml[r][l15] = bfc(mv);
    }

    f32x4 accO[4], accAO[4];
#pragma unroll
    for (int c = 0; c < 4; ++c) {
      accO[c] = z4;
      accAO[c] = z4;
    }
#pragma unroll
    for (int kk = 0; kk < 96; kk += 32) {
      bf16x8 ap = *(const bf16x8*)&Pl[rw + l15][kk + lg * 8];
#pragma unroll
      for (int c = 0; c < 4; ++c) {
        bf16x8 bv = *(const bf16x8*)&Vt[c * 16 + l15][kk + lg * 8];
        accO[c] =
            __builtin_amdgcn_mfma_f32_16x16x32_bf16(ap, bv, accO[c], 0, 0, 0);
      }
    }
    {
      bf16x8 am = *(const bf16x8*)&Ml[rw + l15][lg * 8];
#pragma unroll
      for (int c = 0; c < 4; ++c) {
        bf16x8 bv = *(const bf16x8*)&AUVt[c * 16 + l15][lg * 8];
        accAO[c] =
            __builtin_amdgcn_mfma_f32_16x16x32_bf16(am, bv, accAO[c], 0, 0, 0);
      }
    }
#pragma unroll
    for (int c = 0; c < 4; ++c)
#pragma unroll
      for (int j = 0; j < 4; ++j) {
        int r = rw + lg * 4 + j;
        Pl[r][c * 16 + l15] = bfc(accO[c][j] + g * accAO[c][j]);
      }
    __syncthreads();
#pragma unroll
    for (int i2 = 0; i2 < 2; ++i2) {
      int idx = t + i2 * 256;
      int r = idx >> 3, cg = idx & 7;
      *(int4*)(Ob + (size_t)(b * S_ + q0 + r) * HID_ + h * DH_ + cg * 8) =
          *(const int4*)&Pl[r][cg * 8];
    }
  }
}

// ---------------------------------------------------------------- launcher
extern "C" void kernel_launch(void* const* d_in, const int* in_sizes, int n_in,
                              void* d_out, int out_size, void* d_ws,
                              size_t ws_size, hipStream_t stream) {
  const float* hs = (const float*)d_in[0];
  const float* enc = (const float*)d_in[1];
  const float* au = (const float*)d_in[2];
  const float* Wq = (const float*)d_in[3];
  const float* Wk = (const float*)d_in[4];
  const float* Wv = (const float*)d_in[5];
  const float* Wauk = (const float*)d_in[6];
  const float* Wauv = (const float*)d_in[7];
  const float* Wout = (const float*)d_in[8];
  const float* bout = (const float*)d_in[9];
  const float* temp = (const float*)d_in[10];
  const float* gate = (const float*)d_in[11];
  float* out = (float*)d_out;
  char* ws = (char*)d_ws;

  const size_t szK = (size_t)B_ * KV_ * HID_ * 2;   // 788480
  const size_t szAU = (size_t)B_ * AU_ * HID_ * 2;  // 163840
  const size_t szW640 = (size_t)HID_ * HID_ * 2;    // 819200
  const size_t szW768 = (size_t)HID_ * CROSS_ * 2;  // 983040

  size_t off = 0;
  float* prior = (float*)(ws + off);  off += 16384;
  short* Kbf = (short*)(ws + off);    off += szK;
  short* Vbf = (short*)(ws + off);    off += szK;
  short* AUKbf = (short*)(ws + off);  off += szAU;
  short* AUVbf = (short*)(ws + off);  off += szAU;
  short* Wqt = (short*)(ws + off);    off += szW640;
  short* Wkt = (short*)(ws + off);    off += szW768;
  short* Wvt = (short*)(ws + off);    off += szW768;
  short* Waukt = (short*)(ws + off);  off += szW768;
  short* Wauvt = (short*)(ws + off);  off += szW768;
  short* Woutt = (short*)(ws + off);  off += szW640;
  short* Qbf = (short*)(ws + off);    // 41.94 MB; total ws ~49.5 MB
  short* Abf = Qbf;                   // ALIAS: attn overwrites Q in place
  short* hsb = (short*)d_out;         // d_out head as scratch (dead before
                                      // gemm_out_k writes real output)

  prior_k<<<16, 256, 0, stream>>>(prior);
  wprep_k<<<dim3(10, 12, 6), 256, 0, stream>>>(Wq, Wk, Wv, Wauk, Wauv, Wout,
                                               Wqt, Wkt, Wvt, Waukt, Wauvt,
                                               Woutt);
  cvt_k<<<10240, 256, 0, stream>>>(hs, hsb, (B_ * S_ * HID_) / 8);
  proj4_k<<<dim3(5, 5, 4), 256, 0, stream>>>(enc, au, Wkt, Wvt, Waukt, Wauvt,
                                             Kbf, Vbf, AUKbf, AUVbf);
  gemm_q_k<<<dim3(128, 4), 512, 0, stream>>>(hsb, Wqt, Qbf);
  attn_k<<<dim3(8, HEADS_, B_), 256, 0, stream>>>(Qbf, Kbf, Vbf, AUKbf, AUVbf,
                                                  prior, Abf, temp, gate);
  gemm_out_k<<<dim3(128, 4), 512, 0, stream>>>(Abf, Woutt, out, bout, hs);
}

// Round 12
// 233.152 us; speedup vs baseline: 1.1264x; 1.0671x over previous
//
#include <hip/hip_runtime.h>
#include <hip/hip_bf16.h>

#define B_ 8
#define S_ 4096
#define HID_ 640
#define KV_ 77
#define AU_ 16
#define CROSS_ 768
#define HEADS_ 10
#define DH_ 64
#define SCALE_ 0.125f

using f32x4 = __attribute__((ext_vector_type(4))) float;
using bf16x8 = __attribute__((ext_vector_type(8))) short;

__device__ __forceinline__ short bfc(float f) {
  __hip_bfloat16 h = __float2bfloat16(f);
  return __builtin_bit_cast(short, h);
}

__device__ __forceinline__ void gload16(const void* g, void* lds) {
  __builtin_amdgcn_global_load_lds(
      (const __attribute__((address_space(1))) void*)g,
      (__attribute__((address_space(3))) void*)lds, 16, 0, 0);
}

// ---------------------------------------------------------------- f32 -> bf16
__global__ __launch_bounds__(256) void cvt_k(const float* in, short* out,
                                             int n8) {
  int i = blockIdx.x * 256 + threadIdx.x;
  if (i >= n8) return;
  const float4 a = *(const float4*)(in + (size_t)i * 8);
  const float4 b = *(const float4*)(in + (size_t)i * 8 + 4);
  bf16x8 v;
  v[0] = bfc(a.x); v[1] = bfc(a.y); v[2] = bfc(a.z); v[3] = bfc(a.w);
  v[4] = bfc(b.x); v[5] = bfc(b.y); v[6] = bfc(b.z); v[7] = bfc(b.w);
  *(bf16x8*)(out + (size_t)i * 8) = v;
}

// ------------------------------------------------- weight transpose + convert
__global__ __launch_bounds__(256) void wprep_k(
    const float* Wq, const float* Wk, const float* Wv, const float* Wauk,
    const float* Wauv, const float* Wout, short* Wqt, short* Wkt, short* Wvt,
    short* Waukt, short* Wauvt, short* Woutt) {
  const float* W;
  short* Wt;
  int K;
  switch (blockIdx.z) {
    case 0: W = Wq;   Wt = Wqt;   K = 640; break;
    case 1: W = Wk;   Wt = Wkt;   K = 768; break;
    case 2: W = Wv;   Wt = Wvt;   K = 768; break;
    case 3: W = Wauk; Wt = Waukt; K = 768; break;
    case 4: W = Wauv; Wt = Wauvt; K = 768; break;
    default: W = Wout; Wt = Woutt; K = 640; break;
  }
  int kt = blockIdx.y * 64, nt = blockIdx.x * 64;
  if (kt >= K) return;
  __shared__ short Tl[64][72];
  const int t = threadIdx.x;
#pragma unroll
  for (int j = 0; j < 16; ++j) {
    int i = t + j * 256;
    int r = i >> 6, c = i & 63;
    Tl[c][r] = bfc(W[(size_t)(kt + r) * 640 + nt + c]);
  }
  __syncthreads();
#pragma unroll
  for (int j = 0; j < 2; ++j) {
    int i = t + j * 256;
    int nl = i >> 3, c = i & 7;
    *(int4*)&Wt[(size_t)(nt + nl) * K + kt + c * 8] = *(int4*)&Tl[nl][c * 8];
  }
}

// ---------------------------------------------- big GEMM (EXACT R6 structure)
// 256x128 tile, 512 threads (8 waves, 64x64/wave), BK=64, single-buffer LDS
// (48 KB), gload16 staging, plain __syncthreads loop. Best measured: 71.6 us.
// Swizzle (0 conflicts): row = 128 B = 8 slots of 16 B; physical slot s holds
// logical s^(r&7); read byteoff = (ks*64 + lg*16) ^ ((row&7)<<4).
template <bool EPI>
__device__ __forceinline__ void gemm256(const short* Abf, const short* Bt,
                                        void* Cout, const float* bias,
                                        const float* resid, int N, int m0,
                                        int n0) {
  __shared__ short Al[256 * 64];
  __shared__ short Bl[128 * 64];
  const int t = threadIdx.x;
  const int lane = t & 63;
  const int wave = t >> 6;  // 0..7
  const int l15 = lane & 15, lg = lane >> 4;
  const int wr = (wave >> 1) * 64;
  const int wc = (wave & 1) * 64;

  f32x4 z4 = {0.f, 0.f, 0.f, 0.f};
  f32x4 acc[4][4];
#pragma unroll
  for (int i = 0; i < 4; ++i)
#pragma unroll
    for (int j = 0; j < 4; ++j) acc[i][j] = z4;

  for (int k0 = 0; k0 < 640; k0 += 64) {
#pragma unroll
    for (int i = 0; i < 4; ++i) {
      int chunk = wave * 256 + i * 64 + lane;
      int r = chunk >> 3, s = chunk & 7;
      gload16(Abf + (size_t)(m0 + r) * 640 + k0 + ((s ^ (r & 7)) << 3),
              Al + (size_t)chunk * 8);
    }
#pragma unroll
    for (int i = 0; i < 2; ++i) {
      int chunk = wave * 128 + i * 64 + lane;
      int r = chunk >> 3, s = chunk & 7;
      gload16(Bt + (size_t)(n0 + r) * 640 + k0 + ((s ^ (r & 7)) << 3),
              Bl + (size_t)chunk * 8);
    }
    __syncthreads();
#pragma unroll
    for (int ks = 0; ks < 2; ++ks) {
      bf16x8 af[4], bfr[4];
#pragma unroll
      for (int mi = 0; mi < 4; ++mi) {
        int row = wr + mi * 16 + l15;
        af[mi] = *(const bf16x8*)((const char*)(Al + row * 64) +
                                  ((ks * 64 + lg * 16) ^ ((row & 7) << 4)));
      }
#pragma unroll
      for (int ni = 0; ni < 4; ++ni) {
        int row = wc + ni * 16 + l15;
        bfr[ni] = *(const bf16x8*)((const char*)(Bl + row * 64) +
                                   ((ks * 64 + lg * 16) ^ ((row & 7) << 4)));
      }
#pragma unroll
      for (int mi = 0; mi < 4; ++mi)
#pragma unroll
        for (int ni = 0; ni < 4; ++ni)
          acc[mi][ni] = __builtin_amdgcn_mfma_f32_16x16x32_bf16(
              af[mi], bfr[ni], acc[mi][ni], 0, 0, 0);
    }
    __syncthreads();
  }
#pragma unroll
  for (int mi = 0; mi < 4; ++mi) {
#pragma unroll
    for (int j = 0; j < 4; ++j) {
      int row = m0 + wr + mi * 16 + lg * 4 + j;
#pragma unroll
      for (int ni = 0; ni < 4; ++ni) {
        int col = n0 + wc + ni * 16 + l15;
        size_t idx = (size_t)row * N + col;
        float val = acc[mi][ni][j];
        if (EPI) {
          ((float*)Cout)[idx] = val + bias[col] + resid[idx];
        } else {
          ((short*)Cout)[idx] = bfc(val);
        }
      }
    }
  }
}

__global__ __launch_bounds__(512, 4) void gemm_q_k(const short* A,
                                                   const short* Bt, short* C) {
  gemm256<false>(A, Bt, C, nullptr, nullptr, HID_, blockIdx.x * 256,
                 blockIdx.y * 128);
}

__global__ __launch_bounds__(512, 4) void gemm_out_k(const short* A,
                                                     const short* Bt, float* C,
                                                     const float* bias,
                                                     const float* resid) {
  gemm256<true>(A, Bt, C, bias, resid, HID_, blockIdx.x * 256,
                blockIdx.y * 128);
}

// ---------------------------------------------------------------- small GEMM
__device__ __forceinline__ void gemm_small(const float* A32, const short* Bt,
                                           short* Cout, int M, int K, int N,
                                           int m0, int n0) {
  __shared__ short Al[128][72];
  __shared__ short Bl[128][72];
  const int t = threadIdx.x;
  const int lane = t & 63;
  const int wave = t >> 6;
  const int l15 = lane & 15, lg = lane >> 4;
  const int wr = (wave >> 1) * 64, wc = (wave & 1) * 64;

  f32x4 z4 = {0.f, 0.f, 0.f, 0.f};
  f32x4 acc[4][4];
#pragma unroll
  for (int i = 0; i < 4; ++i)
#pragma unroll
    for (int j = 0; j < 4; ++j) acc[i][j] = z4;

  for (int k0 = 0; k0 < K; k0 += 64) {
#pragma unroll
    for (int j = 0; j < 8; ++j) {
      int i = t + j * 256;
      int r = i >> 4, q = i & 15;
      int row = m0 + r;
      float4 v = {0.f, 0.f, 0.f, 0.f};
      if (row < M) v = *(const float4*)(A32 + (size_t)row * K + k0 + q * 4);
      short4 s;
      s.x = bfc(v.x);
      s.y = bfc(v.y);
      s.z = bfc(v.z);
      s.w = bfc(v.w);
      *(short4*)&Al[r][q * 4] = s;
    }
#pragma unroll
    for (int j = 0; j < 4; ++j) {
      int i = t + j * 256;
      int row = i >> 3, c = i & 7;
      *(int4*)&Bl[row][c * 8] =
          *(const int4*)(Bt + (size_t)(n0 + row) * K + k0 + c * 8);
    }
    __syncthreads();
#pragma unroll
    for (int ks = 0; ks < 64; ks += 32) {
      bf16x8 af[4], bfr[4];
#pragma unroll
      for (int mi = 0; mi < 4; ++mi)
        af[mi] = *(const bf16x8*)&Al[wr + mi * 16 + l15][ks + lg * 8];
#pragma unroll
      for (int ni = 0; ni < 4; ++ni)
        bfr[ni] = *(const bf16x8*)&Bl[wc + ni * 16 + l15][ks + lg * 8];
#pragma unroll
      for (int mi = 0; mi < 4; ++mi)
#pragma unroll
        for (int ni = 0; ni < 4; ++ni)
          acc[mi][ni] = __builtin_amdgcn_mfma_f32_16x16x32_bf16(
              af[mi], bfr[ni], acc[mi][ni], 0, 0, 0);
    }
    __syncthreads();
  }
#pragma unroll
  for (int mi = 0; mi < 4; ++mi) {
#pragma unroll
    for (int j = 0; j < 4; ++j) {
      int row = m0 + wr + mi * 16 + lg * 4 + j;
      if (row >= M) continue;
#pragma unroll
      for (int ni = 0; ni < 4; ++ni) {
        int col = n0 + wc + ni * 16 + l15;
        Cout[(size_t)row * N + col] = bfc(acc[mi][ni][j]);
      }
    }
  }
}

__global__ __launch_bounds__(256) void proj4_k(const float* enc,
                                               const float* au,
                                               const short* Wkt,
                                               const short* Wvt,
                                               const short* Waukt,
                                               const short* Wauvt, short* Kb,
                                               short* Vb, short* AKb,
                                               short* AVb) {
  int z = blockIdx.z;
  const float* A = (z < 2) ? enc : au;
  const short* Bt = (z == 0) ? Wkt : (z == 1) ? Wvt : (z == 2) ? Waukt : Wauvt;
  short* O = (z == 0) ? Kb : (z == 1) ? Vb : (z == 2) ? AKb : AVb;
  int M = (z < 2) ? (B_ * KV_) : (B_ * AU_);
  if ((int)blockIdx.x * 128 >= M) return;
  gemm_small(A, Bt, O, M, CROSS_, HID_, blockIdx.x * 128, blockIdx.y * 128);
}

// ---------------------------------------------------------------- attention
// R12: zero barriers in the q-loop. Wave w stages exactly its own Q rows
// (16w..16w+15) via gload16 + per-wave vmcnt(0); softmax/PV/copy-out touch
// only the wave's own Pl/Ml rows; Kl/Vt/AUKl/AUVt are read-only after the
// single post-staging __syncthreads. Prior computed inline (prior_k removed).
// Ob may alias Qb: wave writes its Q rows only after gload16 read them.
__global__ __launch_bounds__(256) void attn_k(const short* Qb, const short* Kb,
                                              const short* Vb, const short* AKb,
                                              const short* AVb, short* Ob,
                                              const float* temp,
                                              const float* gate) {
  __shared__ short Qt[64 * 64];   // linear, XOR-swizzled (gload16 dest)
  __shared__ short Kl[80][72];
  __shared__ short Vt[64][104];
  __shared__ short Pl[64][104];
  __shared__ short AUKl[16][72];
  __shared__ short AUVt[64][40];
  __shared__ short Ml[64][40];

  const int t = threadIdx.x;
  const int lane = t & 63, wave = t >> 6;
  const int l15 = lane & 15, lg = lane >> 4;
  const int qbase = blockIdx.x * 512;
  const int h = blockIdx.y;
  const int b = blockIdx.z;
  const int rw = wave * 16;
  f32x4 z4 = {0.f, 0.f, 0.f, 0.f};

  // pad zero-init (disjoint from staged writes; covered by the one barrier)
  for (int i = t; i < 64 * 27; i += 256) {
    int r = i / 27, c = i - r * 27;
    Vt[r][77 + c] = 0;
  }
  for (int i = t; i < 64 * 8; i += 256) {
    int r = i >> 3, c = i & 7;
    *(int*)&Pl[r][80 + c * 2] = 0;
  }
  for (int i = t; i < 64 * 12; i += 256) {
    int r = i / 12, c = i - r * 12;
    *(int*)&AUVt[r][16 + c * 2] = 0;
  }
  for (int i = t; i < 64 * 12; i += 256) {
    int r = i / 12, c = i - r * 12;
    *(int*)&Ml[r][16 + c * 2] = 0;
  }
#pragma unroll
  for (int j = 0; j < 3; ++j) {
    int i = t + j * 256;
    if (i < KV_ * 8) {
      int r = i >> 3, c8 = i & 7;
      *(int4*)&Kl[r][c8 * 8] =
          *(const int4*)(Kb + (size_t)(b * KV_ + r) * HID_ + h * DH_ + c8 * 8);
    }
  }
  for (int i = t; i < KV_ * DH_; i += 256) {
    int d = i & 63, kv = i >> 6;
    Vt[d][kv] = Vb[(size_t)(b * KV_ + kv) * HID_ + h * DH_ + d];
  }
  if (t < AU_ * 8) {
    int r = t >> 3, c8 = t & 7;
    *(int4*)&AUKl[r][c8 * 8] =
        *(const int4*)(AKb + (size_t)(b * AU_ + r) * HID_ + h * DH_ + c8 * 8);
  }
  for (int i = t; i < AU_ * DH_; i += 256) {
    int d = i & 63, a = i >> 6;
    AUVt[d][a] = AVb[(size_t)(b * AU_ + a) * HID_ + h * DH_ + d];
  }
  __syncthreads();  // the ONLY block-wide barrier

  const float invT = 1.f / (fabsf(temp[0]) + 1e-6f);
  const float g = gate[0];  // AU_SCALE = 1

  for (int qi = 0; qi < 8; ++qi) {
    const int q0 = qbase + qi * 64;
    // stage own Q rows (16 rows/wave) via gload16, pre-swizzled source
#pragma unroll
    for (int i2 = 0; i2 < 2; ++i2) {
      int chunk = wave * 128 + i2 * 64 + lane;
      int r = chunk >> 3, s = chunk & 7;
      const short* src = Qb + (size_t)(b * S_ + q0 + r) * HID_ + h * DH_ +
                         ((s ^ (r & 7)) << 3);
      gload16(src, Qt + (wave * 128 + i2 * 64) * 8);
    }
    // per-wave wait: only this wave's 2 gload16 (+ finished stores) pending
    asm volatile("s_waitcnt vmcnt(0)" ::: "memory");

    f32x4 accS[5], accA = z4;
#pragma unroll
    for (int c = 0; c < 5; ++c) accS[c] = z4;
#pragma unroll
    for (int ks = 0; ks < 2; ++ks) {
      const char* qrow = (const char*)(Qt + (rw + l15) * 64);
      bf16x8 aq =
          *(const bf16x8*)(qrow + ((ks * 64 + lg * 16) ^ ((l15 & 7) << 4)));
#pragma unroll
      for (int c = 0; c < 5; ++c) {
        bf16x8 bk = *(const bf16x8*)&Kl[c * 16 + l15][ks * 32 + lg * 8];
        accS[c] =
            __builtin_amdgcn_mfma_f32_16x16x32_bf16(aq, bk, accS[c], 0, 0, 0);
      }
      bf16x8 ba = *(const bf16x8*)&AUKl[l15][ks * 32 + lg * 8];
      accA = __builtin_amdgcn_mfma_f32_16x16x32_bf16(aq, ba, accA, 0, 0, 0);
    }

#pragma unroll
    for (int j = 0; j < 4; ++j) {
      float v[5];
      float m = -1e30f;
#pragma unroll
      for (int c = 0; c < 5; ++c) {
        int col = c * 16 + l15;
        v[c] = (col < KV_) ? accS[c][j] * SCALE_ : -1e30f;
        m = fmaxf(m, v[c]);
      }
#pragma unroll
      for (int off = 1; off < 16; off <<= 1) m = fmaxf(m, __shfl_xor(m, off));
      float p[5];
      float s = 0.f;
#pragma unroll
      for (int c = 0; c < 5; ++c) {
        p[c] = (v[c] > -1e29f) ? __expf(v[c] - m) : 0.f;
        s += p[c];
      }
#pragma unroll
      for (int off = 1; off < 16; off <<= 1) s += __shfl_xor(s, off);
      float inv = 1.f / s;
      int r = rw + lg * 4 + j;
#pragma unroll
      for (int c = 0; c < 5; ++c) Pl[r][c * 16 + l15] = bfc(p[c] * inv);
      // AU mask with inline gaussian prior
      int gi = q0 + r;
      float lx = -1.f + 2.f * (float)(gi & 63) / 63.f;
      float ly = -1.f + 2.f * (float)(gi >> 6 & 63) / 63.f;
      float pr = __expf(-(lx * lx + ly * ly) * (1.0f / 0.605f));
      float as = accA[j] * SCALE_ * invT;
      float sg = 1.f / (1.f + __expf(-as));
      float mv = sg * pr * 0.9f + 0.1f;
      Ml[r][l15] = bfc(mv);
    }
    // no barrier: PV reads only this wave's own Pl/Ml rows

    f32x4 accO[4], accAO[4];
#pragma unroll
    for (int c = 0; c < 4; ++c) {
      accO[c] = z4;
      accAO[c] = z4;
    }
#pragma unroll
    for (int kk = 0; kk < 96; kk += 32) {
      bf16x8 ap = *(const bf16x8*)&Pl[rw + l15][kk + lg * 8];
#pragma unroll
      for (int c = 0; c < 4; ++c) {
        bf16x8 bv = *(const bf16x8*)&Vt[c * 16 + l15][kk + lg * 8];
        accO[c] =
            __builtin_amdgcn_mfma_f32_16x16x32_bf16(ap, bv, accO[c], 0, 0, 0);
      }
    }
    {
      bf16x8 am = *(const bf16x8*)&Ml[rw + l15][lg * 8];
#pragma unroll
      for (int c = 0; c < 4; ++c) {
        bf16x8 bv = *(const bf16x8*)&AUVt[c * 16 + l15][lg * 8];
        accAO[c] =
            __builtin_amdgcn_mfma_f32_16x16x32_bf16(am, bv, accAO[c], 0, 0, 0);
      }
    }
    // O tile -> own Pl rows cols 0..63 (P-data dead after PV)
#pragma unroll
    for (int c = 0; c < 4; ++c)
#pragma unroll
      for (int j = 0; j < 4; ++j) {
        int r = rw + lg * 4 + j;
        Pl[r][c * 16 + l15] = bfc(accO[c][j] + g * accAO[c][j]);
      }
    // per-wave coalesced copy-out of OWN 16 rows (no barrier)
#pragma unroll
    for (int i2 = 0; i2 < 2; ++i2) {
      int idx = lane + i2 * 64;
      int r = rw + (idx >> 3), cg = idx & 7;
      *(int4*)(Ob + (size_t)(b * S_ + q0 + r) * HID_ + h * DH_ + cg * 8) =
          *(const int4*)&Pl[r][cg * 8];
    }
  }
}

// ---------------------------------------------------------------- launcher
extern "C" void kernel_launch(void* const* d_in, const int* in_sizes, int n_in,
                              void* d_out, int out_size, void* d_ws,
                              size_t ws_size, hipStream_t stream) {
  const float* hs = (const float*)d_in[0];
  const float* enc = (const float*)d_in[1];
  const float* au = (const float*)d_in[2];
  const float* Wq = (const float*)d_in[3];
  const float* Wk = (const float*)d_in[4];
  const float* Wv = (const float*)d_in[5];
  const float* Wauk = (const float*)d_in[6];
  const float* Wauv = (const float*)d_in[7];
  const float* Wout = (const float*)d_in[8];
  const float* bout = (const float*)d_in[9];
  const float* temp = (const float*)d_in[10];
  const float* gate = (const float*)d_in[11];
  float* out = (float*)d_out;
  char* ws = (char*)d_ws;

  const size_t szK = (size_t)B_ * KV_ * HID_ * 2;   // 788480
  const size_t szAU = (size_t)B_ * AU_ * HID_ * 2;  // 163840
  const size_t szW640 = (size_t)HID_ * HID_ * 2;    // 819200
  const size_t szW768 = (size_t)HID_ * CROSS_ * 2;  // 983040

  size_t off = 0;
  short* Kbf = (short*)(ws + off);    off += szK;
  short* Vbf = (short*)(ws + off);    off += szK;
  short* AUKbf = (short*)(ws + off);  off += szAU;
  short* AUVbf = (short*)(ws + off);  off += szAU;
  short* Wqt = (short*)(ws + off);    off += szW640;
  short* Wkt = (short*)(ws + off);    off += szW768;
  short* Wvt = (short*)(ws + off);    off += szW768;
  short* Waukt = (short*)(ws + off);  off += szW768;
  short* Wauvt = (short*)(ws + off);  off += szW768;
  short* Woutt = (short*)(ws + off);  off += szW640;
  short* Qbf = (short*)(ws + off);    // 41.94 MB; total ws ~49.5 MB
  short* Abf = Qbf;                   // ALIAS: attn overwrites Q in place
  short* hsb = (short*)d_out;         // d_out head as scratch (dead before
                                      // gemm_out_k writes real output)

  wprep_k<<<dim3(10, 12, 6), 256, 0, stream>>>(Wq, Wk, Wv, Wauk, Wauv, Wout,
                                               Wqt, Wkt, Wvt, Waukt, Wauvt,
                                               Woutt);
  cvt_k<<<10240, 256, 0, stream>>>(hs, hsb, (B_ * S_ * HID_) / 8);
  proj4_k<<<dim3(5, 5, 4), 256, 0, stream>>>(enc, au, Wkt, Wvt, Waukt, Wauvt,
                                             Kbf, Vbf, AUKbf, AUVbf);
  gemm_q_k<<<dim3(128, 5), 512, 0, stream>>>(hsb, Wqt, Qbf);
  attn_k<<<dim3(8, HEADS_, B_), 256, 0, stream>>>(Qbf, Kbf, Vbf, AUKbf, AUVbf,
                                                  Abf, temp, gate);
  gemm_out_k<<<dim3(128, 5), 512, 0, stream>>>(Abf, Woutt, out, bout, hs);
}

// Round 13
// 227.023 us; speedup vs baseline: 1.1569x; 1.0270x over previous
//
#include <hip/hip_runtime.h>
#include <hip/hip_bf16.h>

#define B_ 8
#define S_ 4096
#define HID_ 640
#define KV_ 77
#define AU_ 16
#define CROSS_ 768
#define HEADS_ 10
#define DH_ 64
#define SCALE_ 0.125f

using f32x4 = __attribute__((ext_vector_type(4))) float;
using bf16x8 = __attribute__((ext_vector_type(8))) short;

__device__ __forceinline__ short bfc(float f) {
  __hip_bfloat16 h = __float2bfloat16(f);
  return __builtin_bit_cast(short, h);
}

__device__ __forceinline__ float bf2f(short s) {
  unsigned u = ((unsigned)(unsigned short)s) << 16;
  return __uint_as_float(u);
}

__device__ __forceinline__ void gload16(const void* g, void* lds) {
  __builtin_amdgcn_global_load_lds(
      (const __attribute__((address_space(1))) void*)g,
      (__attribute__((address_space(3))) void*)lds, 16, 0, 0);
}

// ------------------------------------- prep: weight transpose + hs f32->bf16
// blocks [0, 10240): cvt hs -> hsb (8 f32/thread)
// blocks [10240, 10960): wprep (720 = 10 x 12 x 6)
__global__ __launch_bounds__(256) void prep_k(
    const float* hs, short* hsb, const float* Wq, const float* Wk,
    const float* Wv, const float* Wauk, const float* Wauv, const float* Wout,
    short* Wqt, short* Wkt, short* Wvt, short* Waukt, short* Wauvt,
    short* Woutt) {
  __shared__ short Tl[64][72];
  const int t = threadIdx.x;
  int bid = blockIdx.x;
  if (bid < 10240) {
    int i = bid * 256 + t;
    const float4 a = *(const float4*)(hs + (size_t)i * 8);
    const float4 b = *(const float4*)(hs + (size_t)i * 8 + 4);
    bf16x8 v;
    v[0] = bfc(a.x); v[1] = bfc(a.y); v[2] = bfc(a.z); v[3] = bfc(a.w);
    v[4] = bfc(b.x); v[5] = bfc(b.y); v[6] = bfc(b.z); v[7] = bfc(b.w);
    *(bf16x8*)(hsb + (size_t)i * 8) = v;
    return;
  }
  int wb = bid - 10240;
  int z = wb / 120;
  int rem = wb - z * 120;
  int ky = rem / 10, nx = rem - ky * 10;
  const float* W;
  short* Wt;
  int K;
  switch (z) {
    case 0: W = Wq;   Wt = Wqt;   K = 640; break;
    case 1: W = Wk;   Wt = Wkt;   K = 768; break;
    case 2: W = Wv;   Wt = Wvt;   K = 768; break;
    case 3: W = Wauk; Wt = Waukt; K = 768; break;
    case 4: W = Wauv; Wt = Wauvt; K = 768; break;
    default: W = Wout; Wt = Woutt; K = 640; break;
  }
  int kt = ky * 64, nt = nx * 64;
  if (kt >= K) return;
#pragma unroll
  for (int j = 0; j < 16; ++j) {
    int i = t + j * 256;
    int r = i >> 6, c = i & 63;
    Tl[c][r] = bfc(W[(size_t)(kt + r) * 640 + nt + c]);
  }
  __syncthreads();
#pragma unroll
  for (int j = 0; j < 2; ++j) {
    int i = t + j * 256;
    int nl = i >> 3, c = i & 7;
    *(int4*)&Wt[(size_t)(nt + nl) * K + kt + c * 8] = *(int4*)&Tl[nl][c * 8];
  }
}

// ---------------------------------------------- big GEMM (EXACT R6 structure)
// 256x128 tile, 512 threads, BK=64, single-buffer LDS (48 KB), gload16
// staging, plain __syncthreads loop. Best measured: 71.6 us.
// Swizzle (0 conflicts): row = 128 B = 8 slots of 16 B; physical slot s holds
// logical s^(r&7); read byteoff = (ks*64 + lg*16) ^ ((row&7)<<4).
// EPI: 0 = bf16 C out; 1 = f32 C with bias + f32 resid; 2 = f32 C with bias +
// bf16 resid.
template <int EPI>
__device__ __forceinline__ void gemm256(const short* Abf, const short* Bt,
                                        void* Cout, const float* bias,
                                        const void* resid, int N, int m0,
                                        int n0) {
  __shared__ short Al[256 * 64];
  __shared__ short Bl[128 * 64];
  const int t = threadIdx.x;
  const int lane = t & 63;
  const int wave = t >> 6;  // 0..7
  const int l15 = lane & 15, lg = lane >> 4;
  const int wr = (wave >> 1) * 64;
  const int wc = (wave & 1) * 64;

  f32x4 z4 = {0.f, 0.f, 0.f, 0.f};
  f32x4 acc[4][4];
#pragma unroll
  for (int i = 0; i < 4; ++i)
#pragma unroll
    for (int j = 0; j < 4; ++j) acc[i][j] = z4;

  for (int k0 = 0; k0 < 640; k0 += 64) {
#pragma unroll
    for (int i = 0; i < 4; ++i) {
      int chunk = wave * 256 + i * 64 + lane;
      int r = chunk >> 3, s = chunk & 7;
      gload16(Abf + (size_t)(m0 + r) * 640 + k0 + ((s ^ (r & 7)) << 3),
              Al + (size_t)chunk * 8);
    }
#pragma unroll
    for (int i = 0; i < 2; ++i) {
      int chunk = wave * 128 + i * 64 + lane;
      int r = chunk >> 3, s = chunk & 7;
      gload16(Bt + (size_t)(n0 + r) * 640 + k0 + ((s ^ (r & 7)) << 3),
              Bl + (size_t)chunk * 8);
    }
    __syncthreads();
#pragma unroll
    for (int ks = 0; ks < 2; ++ks) {
      bf16x8 af[4], bfr[4];
#pragma unroll
      for (int mi = 0; mi < 4; ++mi) {
        int row = wr + mi * 16 + l15;
        af[mi] = *(const bf16x8*)((const char*)(Al + row * 64) +
                                  ((ks * 64 + lg * 16) ^ ((row & 7) << 4)));
      }
#pragma unroll
      for (int ni = 0; ni < 4; ++ni) {
        int row = wc + ni * 16 + l15;
        bfr[ni] = *(const bf16x8*)((const char*)(Bl + row * 64) +
                                   ((ks * 64 + lg * 16) ^ ((row & 7) << 4)));
      }
#pragma unroll
      for (int mi = 0; mi < 4; ++mi)
#pragma unroll
        for (int ni = 0; ni < 4; ++ni)
          acc[mi][ni] = __builtin_amdgcn_mfma_f32_16x16x32_bf16(
              af[mi], bfr[ni], acc[mi][ni], 0, 0, 0);
    }
    __syncthreads();
  }
#pragma unroll
  for (int mi = 0; mi < 4; ++mi) {
#pragma unroll
    for (int j = 0; j < 4; ++j) {
      int row = m0 + wr + mi * 16 + lg * 4 + j;
#pragma unroll
      for (int ni = 0; ni < 4; ++ni) {
        int col = n0 + wc + ni * 16 + l15;
        size_t idx = (size_t)row * N + col;
        float val = acc[mi][ni][j];
        if (EPI == 1) {
          ((float*)Cout)[idx] = val + bias[col] + ((const float*)resid)[idx];
        } else if (EPI == 2) {
          ((float*)Cout)[idx] = val + bias[col] + bf2f(((const short*)resid)[idx]);
        } else {
          ((short*)Cout)[idx] = bfc(val);
        }
      }
    }
  }
}

__global__ __launch_bounds__(512, 4) void gemm_q_k(const short* A,
                                                   const short* Bt, short* C) {
  gemm256<0>(A, Bt, C, nullptr, nullptr, HID_, blockIdx.x * 256,
             blockIdx.y * 128);
}

__global__ __launch_bounds__(512, 4) void gemm_out_f32r(const short* A,
                                                        const short* Bt,
                                                        float* C,
                                                        const float* bias,
                                                        const float* resid) {
  gemm256<1>(A, Bt, C, bias, resid, HID_, blockIdx.x * 256, blockIdx.y * 128);
}

__global__ __launch_bounds__(512, 4) void gemm_out_b16r(const short* A,
                                                        const short* Bt,
                                                        float* C,
                                                        const float* bias,
                                                        const short* resid) {
  gemm256<2>(A, Bt, C, bias, resid, HID_, blockIdx.x * 256, blockIdx.y * 128);
}

// ---------------------------------------------------------------- small GEMM
__device__ __forceinline__ void gemm_small(const float* A32, const short* Bt,
                                           short* Cout, int M, int K, int N,
                                           int m0, int n0) {
  __shared__ short Al[128][72];
  __shared__ short Bl[128][72];
  const int t = threadIdx.x;
  const int lane = t & 63;
  const int wave = t >> 6;
  const int l15 = lane & 15, lg = lane >> 4;
  const int wr = (wave >> 1) * 64, wc = (wave & 1) * 64;

  f32x4 z4 = {0.f, 0.f, 0.f, 0.f};
  f32x4 acc[4][4];
#pragma unroll
  for (int i = 0; i < 4; ++i)
#pragma unroll
    for (int j = 0; j < 4; ++j) acc[i][j] = z4;

  for (int k0 = 0; k0 < K; k0 += 64) {
#pragma unroll
    for (int j = 0; j < 8; ++j) {
      int i = t + j * 256;
      int r = i >> 4, q = i & 15;
      int row = m0 + r;
      float4 v = {0.f, 0.f, 0.f, 0.f};
      if (row < M) v = *(const float4*)(A32 + (size_t)row * K + k0 + q * 4);
      short4 s;
      s.x = bfc(v.x);
      s.y = bfc(v.y);
      s.z = bfc(v.z);
      s.w = bfc(v.w);
      *(short4*)&Al[r][q * 4] = s;
    }
#pragma unroll
    for (int j = 0; j < 4; ++j) {
      int i = t + j * 256;
      int row = i >> 3, c = i & 7;
      *(int4*)&Bl[row][c * 8] =
          *(const int4*)(Bt + (size_t)(n0 + row) * K + k0 + c * 8);
    }
    __syncthreads();
#pragma unroll
    for (int ks = 0; ks < 64; ks += 32) {
      bf16x8 af[4], bfr[4];
#pragma unroll
      for (int mi = 0; mi < 4; ++mi)
        af[mi] = *(const bf16x8*)&Al[wr + mi * 16 + l15][ks + lg * 8];
#pragma unroll
      for (int ni = 0; ni < 4; ++ni)
        bfr[ni] = *(const bf16x8*)&Bl[wc + ni * 16 + l15][ks + lg * 8];
#pragma unroll
      for (int mi = 0; mi < 4; ++mi)
#pragma unroll
        for (int ni = 0; ni < 4; ++ni)
          acc[mi][ni] = __builtin_amdgcn_mfma_f32_16x16x32_bf16(
              af[mi], bfr[ni], acc[mi][ni], 0, 0, 0);
    }
    __syncthreads();
  }
#pragma unroll
  for (int mi = 0; mi < 4; ++mi) {
#pragma unroll
    for (int j = 0; j < 4; ++j) {
      int row = m0 + wr + mi * 16 + lg * 4 + j;
      if (row >= M) continue;
#pragma unroll
      for (int ni = 0; ni < 4; ++ni) {
        int col = n0 + wc + ni * 16 + l15;
        Cout[(size_t)row * N + col] = bfc(acc[mi][ni][j]);
      }
    }
  }
}

__global__ __launch_bounds__(256) void proj4_k(const float* enc,
                                               const float* au,
                                               const short* Wkt,
                                               const short* Wvt,
                                               const short* Waukt,
                                               const short* Wauvt, short* Kb,
                                               short* Vb, short* AKb,
                                               short* AVb) {
  int z = blockIdx.z;
  const float* A = (z < 2) ? enc : au;
  const short* Bt = (z == 0) ? Wkt : (z == 1) ? Wvt : (z == 2) ? Waukt : Wauvt;
  short* O = (z == 0) ? Kb : (z == 1) ? Vb : (z == 2) ? AKb : AVb;
  int M = (z < 2) ? (B_ * KV_) : (B_ * AU_);
  if ((int)blockIdx.x * 128 >= M) return;
  gemm_small(A, Bt, O, M, CROSS_, HID_, blockIdx.x * 128, blockIdx.y * 128);
}

// ---------------------------------------------------------------- attention
// R12 structure (best): zero barriers in the q-loop; wave-local everything;
// inline gaussian prior; Ob may alias Qb (race-free; see R6/R12 analysis).
__global__ __launch_bounds__(256) void attn_k(const short* Qb, const short* Kb,
                                              const short* Vb, const short* AKb,
                                              const short* AVb, short* Ob,
                                              const float* temp,
                                              const float* gate) {
  __shared__ short Qt[64 * 64];   // linear, XOR-swizzled (gload16 dest)
  __shared__ short Kl[80][72];
  __shared__ short Vt[64][104];
  __shared__ short Pl[64][104];
  __shared__ short AUKl[16][72];
  __shared__ short AUVt[64][40];
  __shared__ short Ml[64][40];

  const int t = threadIdx.x;
  const int lane = t & 63, wave = t >> 6;
  const int l15 = lane & 15, lg = lane >> 4;
  const int qbase = blockIdx.x * 512;
  const int h = blockIdx.y;
  const int b = blockIdx.z;
  const int rw = wave * 16;
  f32x4 z4 = {0.f, 0.f, 0.f, 0.f};

  for (int i = t; i < 64 * 27; i += 256) {
    int r = i / 27, c = i - r * 27;
    Vt[r][77 + c] = 0;
  }
  for (int i = t; i < 64 * 8; i += 256) {
    int r = i >> 3, c = i & 7;
    *(int*)&Pl[r][80 + c * 2] = 0;
  }
  for (int i = t; i < 64 * 12; i += 256) {
    int r = i / 12, c = i - r * 12;
    *(int*)&AUVt[r][16 + c * 2] = 0;
  }
  for (int i = t; i < 64 * 12; i += 256) {
    int r = i / 12, c = i - r * 12;
    *(int*)&Ml[r][16 + c * 2] = 0;
  }
#pragma unroll
  for (int j = 0; j < 3; ++j) {
    int i = t + j * 256;
    if (i < KV_ * 8) {
      int r = i >> 3, c8 = i & 7;
      *(int4*)&Kl[r][c8 * 8] =
          *(const int4*)(Kb + (size_t)(b * KV_ + r) * HID_ + h * DH_ + c8 * 8);
    }
  }
  for (int i = t; i < KV_ * DH_; i += 256) {
    int d = i & 63, kv = i >> 6;
    Vt[d][kv] = Vb[(size_t)(b * KV_ + kv) * HID_ + h * DH_ + d];
  }
  if (t < AU_ * 8) {
    int r = t >> 3, c8 = t & 7;
    *(int4*)&AUKl[r][c8 * 8] =
        *(const int4*)(AKb + (size_t)(b * AU_ + r) * HID_ + h * DH_ + c8 * 8);
  }
  for (int i = t; i < AU_ * DH_; i += 256) {
    int d = i & 63, a = i >> 6;
    AUVt[d][a] = AVb[(size_t)(b * AU_ + a) * HID_ + h * DH_ + d];
  }
  __syncthreads();  // the ONLY block-wide barrier

  const float invT = 1.f / (fabsf(temp[0]) + 1e-6f);
  const float g = gate[0];  // AU_SCALE = 1

  for (int qi = 0; qi < 8; ++qi) {
    const int q0 = qbase + qi * 64;
#pragma unroll
    for (int i2 = 0; i2 < 2; ++i2) {
      int chunk = wave * 128 + i2 * 64 + lane;
      int r = chunk >> 3, s = chunk & 7;
      const short* src = Qb + (size_t)(b * S_ + q0 + r) * HID_ + h * DH_ +
                         ((s ^ (r & 7)) << 3);
      gload16(src, Qt + (wave * 128 + i2 * 64) * 8);
    }
    asm volatile("s_waitcnt vmcnt(0)" ::: "memory");

    f32x4 accS[5], accA = z4;
#pragma unroll
    for (int c = 0; c < 5; ++c) accS[c] = z4;
#pragma unroll
    for (int ks = 0; ks < 2; ++ks) {
      const char* qrow = (const char*)(Qt + (rw + l15) * 64);
      bf16x8 aq =
          *(const bf16x8*)(qrow + ((ks * 64 + lg * 16) ^ ((l15 & 7) << 4)));
#pragma unroll
      for (int c = 0; c < 5; ++c) {
        bf16x8 bk = *(const bf16x8*)&Kl[c * 16 + l15][ks * 32 + lg * 8];
        accS[c] =
            __builtin_amdgcn_mfma_f32_16x16x32_bf16(aq, bk, accS[c], 0, 0, 0);
      }
      bf16x8 ba = *(const bf16x8*)&AUKl[l15][ks * 32 + lg * 8];
      accA = __builtin_amdgcn_mfma_f32_16x16x32_bf16(aq, ba, accA, 0, 0, 0);
    }

#pragma unroll
    for (int j = 0; j < 4; ++j) {
      float v[5];
      float m = -1e30f;
#pragma unroll
      for (int c = 0; c < 5; ++c) {
        int col = c * 16 + l15;
        v[c] = (col < KV_) ? accS[c][j] * SCALE_ : -1e30f;
        m = fmaxf(m, v[c]);
      }
#pragma unroll
      for (int off = 1; off < 16; off <<= 1) m = fmaxf(m, __shfl_xor(m, off));
      float p[5];
      float s = 0.f;
#pragma unroll
      for (int c = 0; c < 5; ++c) {
        p[c] = (v[c] > -1e29f) ? __expf(v[c] - m) : 0.f;
        s += p[c];
      }
#pragma unroll
      for (int off = 1; off < 16; off <<= 1) s += __shfl_xor(s, off);
      float inv = 1.f / s;
      int r = rw + lg * 4 + j;
#pragma unroll
      for (int c = 0; c < 5; ++c) Pl[r][c * 16 + l15] = bfc(p[c] * inv);
      int gi = q0 + r;
      float lx = -1.f + 2.f * (float)(gi & 63) / 63.f;
      float ly = -1.f + 2.f * (float)(gi >> 6 & 63) / 63.f;
      float pr = __expf(-(lx * lx + ly * ly) * (1.0f / 0.605f));
      float as = accA[j] * SCALE_ * invT;
      float sg = 1.f / (1.f + __expf(-as));
      float mv = sg * pr * 0.9f + 0.1f;
      Ml[r][l15] = bfc(mv);
    }

    f32x4 accO[4], accAO[4];
#pragma unroll
    for (int c = 0; c < 4; ++c) {
      accO[c] = z4;
      accAO[c] = z4;
    }
#pragma unroll
    for (int kk = 0; kk < 96; kk += 32) {
      bf16x8 ap = *(const bf16x8*)&Pl[rw + l15][kk + lg * 8];
#pragma unroll
      for (int c = 0; c < 4; ++c) {
        bf16x8 bv = *(const bf16x8*)&Vt[c * 16 + l15][kk + lg * 8];
        accO[c] =
            __builtin_amdgcn_mfma_f32_16x16x32_bf16(ap, bv, accO[c], 0, 0, 0);
      }
    }
    {
      bf16x8 am = *(const bf16x8*)&Ml[rw + l15][lg * 8];
#pragma unroll
      for (int c = 0; c < 4; ++c) {
        bf16x8 bv = *(const bf16x8*)&AUVt[c * 16 + l15][lg * 8];
        accAO[c] =
            __builtin_amdgcn_mfma_f32_16x16x32_bf16(am, bv, accAO[c], 0, 0, 0);
      }
    }
#pragma unroll
    for (int c = 0; c < 4; ++c)
#pragma unroll
      for (int j = 0; j < 4; ++j) {
        int r = rw + lg * 4 + j;
        Pl[r][c * 16 + l15] = bfc(accO[c][j] + g * accAO[c][j]);
      }
#pragma unroll
    for (int i2 = 0; i2 < 2; ++i2) {
      int idx = lane + i2 * 64;
      int r = rw + (idx >> 3), cg = idx & 7;
      *(int4*)(Ob + (size_t)(b * S_ + q0 + r) * HID_ + h * DH_ + cg * 8) =
          *(const int4*)&Pl[r][cg * 8];
    }
  }
}

// ---------------------------------------------------------------- launcher
extern "C" void kernel_launch(void* const* d_in, const int* in_sizes, int n_in,
                              void* d_out, int out_size, void* d_ws,
                              size_t ws_size, hipStream_t stream) {
  const float* hs = (const float*)d_in[0];
  const float* enc = (const float*)d_in[1];
  const float* au = (const float*)d_in[2];
  const float* Wq = (const float*)d_in[3];
  const float* Wk = (const float*)d_in[4];
  const float* Wv = (const float*)d_in[5];
  const float* Wauk = (const float*)d_in[6];
  const float* Wauv = (const float*)d_in[7];
  const float* Wout = (const float*)d_in[8];
  const float* bout = (const float*)d_in[9];
  const float* temp = (const float*)d_in[10];
  const float* gate = (const float*)d_in[11];
  float* out = (float*)d_out;
  char* ws = (char*)d_ws;

  const size_t szK = (size_t)B_ * KV_ * HID_ * 2;   // 788480
  const size_t szAU = (size_t)B_ * AU_ * HID_ * 2;  // 163840
  const size_t szW640 = (size_t)HID_ * HID_ * 2;    // 819200
  const size_t szW768 = (size_t)HID_ * CROSS_ * 2;  // 983040
  const size_t szHS = (size_t)B_ * S_ * HID_ * 2;   // 41943040

  size_t off = 0;
  short* Kbf = (short*)(ws + off);    off += szK;
  short* Vbf = (short*)(ws + off);    off += szK;
  short* AUKbf = (short*)(ws + off);  off += szAU;
  short* AUVbf = (short*)(ws + off);  off += szAU;
  short* Wqt = (short*)(ws + off);    off += szW640;
  short* Wkt = (short*)(ws + off);    off += szW768;
  short* Wvt = (short*)(ws + off);    off += szW768;
  short* Waukt = (short*)(ws + off);  off += szW768;
  short* Wauvt = (short*)(ws + off);  off += szW768;
  short* Woutt = (short*)(ws + off);  off += szW640;
  short* Qbf = (short*)(ws + off);    off += szHS;  // 49.4 MB so far
  short* Abf = Qbf;                   // ALIAS: attn overwrites Q in place

  // hsb: prefer ws (enables bf16 resid in gemm_out, halving resid traffic);
  // fall back to d_out-head scratch (then resid must read f32 hs to avoid
  // read/write aliasing with the final output).
  bool hsb_in_ws = (ws_size >= off + szHS);
  short* hsb = hsb_in_ws ? (short*)(ws + off) : (short*)d_out;

  prep_k<<<10960, 256, 0, stream>>>(hs, hsb, Wq, Wk, Wv, Wauk, Wauv, Wout,
                                    Wqt, Wkt, Wvt, Waukt, Wauvt, Woutt);
  proj4_k<<<dim3(5, 5, 4), 256, 0, stream>>>(enc, au, Wkt, Wvt, Waukt, Wauvt,
                                             Kbf, Vbf, AUKbf, AUVbf);
  gemm_q_k<<<dim3(128, 5), 512, 0, stream>>>(hsb, Wqt, Qbf);
  attn_k<<<dim3(8, HEADS_, B_), 256, 0, stream>>>(Qbf, Kbf, Vbf, AUKbf, AUVbf,
                                                  Abf, temp, gate);
  if (hsb_in_ws) {
    gemm_out_b16r<<<dim3(128, 5), 512, 0, stream>>>(Abf, Woutt, out, bout,
                                                    hsb);
  } else {
    gemm_out_f32r<<<dim3(128, 5), 512, 0, stream>>>(Abf, Woutt, out, bout,
                                                    hs);
  }
}